// Round 17
// baseline (145.307 us; speedup 1.0000x reference)
//
#include <hip/hip_runtime.h>
#include <math.h>

// ws float-offset layout (ws >= 1 GiB, we use ~70 MB):
// xavg  [0, 16384)
// xmax  [16384, 32768)
// ypart [32768, 294912)        16 slots x 16384: slot = c*4 + dquarter
// PD    [294912, +4194304)     delta     [c][b][chunk][t][d]  (64x64 tiles, t-major)
// PX    PD+4194304             delta*xi  [t][d]
// PG    PX+4194304             g         [t][d]
// BCB   PG+4194304 (+524288)   B [c][b][chunk][s][t]
// BCC   BCB+524288             C [c][b][chunk][s][t]
// YB    BCC+524288 (+65536)    ybase [c][b][t]
// CONST YB+65536 (+2048)       per c (320): u[128], v[128], wf[64]
// HE    CONST+2048 (+1048576)  chunk-end states  [(c*4+dq)*32+b][chunk][256]
// AP    HE+1048576             chunk decay aP
// HIN   AP+1048576             chunk incoming states
#define OFF_YPART 32768
#define OFF_PD    294912
#define OFF_PX    (OFF_PD + 4194304)
#define OFF_PG    (OFF_PX + 4194304)
#define OFF_BCB   (OFF_PG + 4194304)
#define OFF_BCC   (OFF_BCB + 524288)
#define OFF_YB    (OFF_BCC + 524288)
#define OFF_CONST (OFF_YB + 65536)
#define OFF_HE    (OFF_CONST + 2048)
#define OFF_AP    (OFF_HE + 1048576)
#define OFF_HIN   (OFF_AP + 1048576)

__global__ __launch_bounds__(256) void kreduce(const float* __restrict__ in,
                                               float* __restrict__ xavg,
                                               float* __restrict__ xmax) {
    const int bl = blockIdx.x;            // 0..16383  (= b*512 + l)
    const float* p = in + (size_t)bl * 4096;
    const int t = threadIdx.x;
    float s = 0.f, m = -INFINITY;
#pragma unroll
    for (int it = 0; it < 4; ++it) {
        float4 v = *reinterpret_cast<const float4*>(p + (size_t)(it * 256 + t) * 4);
        s += v.x + v.y + v.z + v.w;
        m = fmaxf(m, fmaxf(fmaxf(v.x, v.y), fmaxf(v.z, v.w)));
    }
#pragma unroll
    for (int o = 1; o < 64; o <<= 1) {
        s += __shfl_xor(s, o);
        m = fmaxf(m, __shfl_xor(m, o));
    }
    __shared__ float ls[4], lm[4];
    const int w = t >> 6;
    if ((t & 63) == 0) { ls[w] = s; lm[w] = m; }
    __syncthreads();
    if (t == 0) {
        s = ls[0] + ls[1] + ls[2] + ls[3];
        m = fmaxf(fmaxf(lm[0], lm[1]), fmaxf(lm[2], lm[3]));
        xavg[bl] = s * (1.f / 4096.f);
        xmax[bl] = m;
    }
}

// kconst: per-call folded weights (u, v, wfold) computed once. 4 blocks x 128 thr.
__global__ __launch_bounds__(128) void kconst(
    float* __restrict__ ws,
    const float* __restrict__ paw, const float* __restrict__ pab,
    const float* __restrict__ pmw, const float* __restrict__ pmb,
    const float* __restrict__ outw_outer,
    const float* __restrict__ f_in_w, const float* __restrict__ f_out_w,
    const float* __restrict__ b_in_w, const float* __restrict__ b_out_w)
{
    const int c = blockIdx.x;
    const int t = threadIdx.x;
    const int strm = c >> 1, dir = c & 1;
    const float* in_w = dir ? b_in_w : f_in_w;
    const float* owp  = dir ? b_out_w : f_out_w;
    const float* projw = strm ? pmw : paw;
    const float* projb = strm ? pmb : pab;

    float u = 0.f, v = 0.f;
    const float* row = in_w + t * 32;
#pragma unroll
    for (int m = 0; m < 32; ++m) {
        u = fmaf(row[m], projw[m], u);
        v = fmaf(row[m], projb[m], v);
    }
    ws[OFF_CONST + c * 320 + t] = u;
    ws[OFF_CONST + c * 320 + 128 + t] = v;
    if (t < 64) {
        float wf = 0.f;
#pragma unroll
        for (int m = 0; m < 32; ++m) wf = fmaf(outw_outer[m], owp[m * 64 + t], wf);
        ws[OFF_CONST + c * 320 + 256 + t] = wf;
    }
}

// slot of dbc j-index (j: 0,1=dt; 2..17=B; 18..33=C) in interleaved record
__device__ __forceinline__ int dbc_slot(int j) {
    return j < 2 ? j : (j < 18 ? 2 * j - 2 : 2 * j - 33);
}

// kprep: A-phases + full A3 precompute. (unchanged from r16)
__global__ __launch_bounds__(512, 4) void kprep(
    const float* __restrict__ xavg, const float* __restrict__ xmax,
    float* __restrict__ ws,
    const float* __restrict__ f_conv_w, const float* __restrict__ f_conv_b,
    const float* __restrict__ f_xproj_w, const float* __restrict__ f_dt_w,
    const float* __restrict__ f_dt_b, const float* __restrict__ f_D,
    const float* __restrict__ b_conv_w, const float* __restrict__ b_conv_b,
    const float* __restrict__ b_xproj_w, const float* __restrict__ b_dt_w,
    const float* __restrict__ b_dt_b, const float* __restrict__ b_D)
{
    const int tid = threadIdx.x;
    const int c  = blockIdx.x >> 8;
    const int b  = (blockIdx.x >> 3) & 31;
    const int cq = blockIdx.x & 7;
    const int strm = c >> 1, dir = c & 1;

    const float* cwp  = dir ? b_conv_w : f_conv_w;
    const float* cbp  = dir ? b_conv_b : f_conv_b;
    const float* xpw  = dir ? b_xproj_w: f_xproj_w;
    const float* dtwp = dir ? b_dt_w   : f_dt_w;
    const float* dtbp = dir ? b_dt_b   : f_dt_b;
    const float* Dpar = dir ? b_D      : f_D;
    const float* xin  = strm ? xmax : xavg;

    __shared__ float sseq4[68];
    __shared__ float su[128], sv[128];
    __shared__ float scw[64][4], scb[64], sdtw[64][2], sdtb[64], sD[64], swf[64];
    __shared__ float sxp[34][68];
    __shared__ float sxi[64][68];
    __shared__ float sdbc[64][37];

    if (tid < 67) {
        int g = cq * 64 - 3 + tid;
        float val = 0.f;
        if (g >= 0) val = xin[b * 512 + (dir ? (511 - g) : g)];
        sseq4[tid] = val;
    }
    if (tid < 128) {
        su[tid] = ws[OFF_CONST + c * 320 + tid];
        sv[tid] = ws[OFF_CONST + c * 320 + 128 + tid];
    }
    if (tid < 64) {
#pragma unroll
        for (int k = 0; k < 4; ++k) scw[tid][k] = cwp[tid * 4 + k];
        scb[tid] = cbp[tid];
        sdtw[tid][0] = dtwp[tid * 2];
        sdtw[tid][1] = dtwp[tid * 2 + 1];
        sdtb[tid] = dtbp[tid];
        sD[tid] = Dpar[tid];
        swf[tid] = ws[OFF_CONST + c * 320 + 256 + tid];
    }
    for (int i = tid; i < 34 * 64; i += 512) sxp[i >> 6][i & 63] = xpw[i];
    __syncthreads();

    const int ll8 = tid >> 3;
    const int j8  = tid & 7;
    const int gi  = cq * 64 + ll8;

    // A1: xi for all 64 d
    {
        float t0 = sseq4[ll8], t1 = sseq4[ll8 + 1], t2 = sseq4[ll8 + 2], t3 = sseq4[ll8 + 3];
        float vv0 = (gi >= 3) ? 1.f : 0.f;
        float vv1 = (gi >= 2) ? 1.f : 0.f;
        float vv2 = (gi >= 1) ? 1.f : 0.f;
#pragma unroll
        for (int k = 0; k < 8; ++k) {
            int di = j8 * 8 + k;
            float u = su[di], v = sv[di];
            float xc = scw[di][0] * fmaf(t0, u, vv0 * v)
                     + scw[di][1] * fmaf(t1, u, vv1 * v)
                     + scw[di][2] * fmaf(t2, u, vv2 * v)
                     + scw[di][3] * fmaf(t3, u, v);
            xc += scb[di];
            float sig = 1.f / (1.f + __expf(-xc));
            sxi[ll8][di] = xc * sig;
        }
    }
    __syncthreads();

    // A2: dbc = xi @ xproj_w.T (unroll 2: spill discipline, r2-r9 lesson)
    {
        float a0 = 0.f, a1 = 0.f, a2 = 0.f, a3 = 0.f, a4 = 0.f;
        const float4* xr4 = reinterpret_cast<const float4*>(&sxi[ll8][0]);
        const float4* r0 = reinterpret_cast<const float4*>(&sxp[j8 + 0][0]);
        const float4* r1 = reinterpret_cast<const float4*>(&sxp[j8 + 8][0]);
        const float4* r2 = reinterpret_cast<const float4*>(&sxp[j8 + 16][0]);
        const float4* r3 = reinterpret_cast<const float4*>(&sxp[j8 + 24][0]);
        const float4* r4 = (j8 < 2) ? reinterpret_cast<const float4*>(&sxp[j8 + 32][0]) : r0;
        bool extra = (j8 < 2);
#pragma unroll 2
        for (int q = 0; q < 16; ++q) {
            float4 x = xr4[q];
            float4 w;
            w = r0[q]; a0 = fmaf(x.x,w.x,fmaf(x.y,w.y,fmaf(x.z,w.z,fmaf(x.w,w.w,a0))));
            w = r1[q]; a1 = fmaf(x.x,w.x,fmaf(x.y,w.y,fmaf(x.z,w.z,fmaf(x.w,w.w,a1))));
            w = r2[q]; a2 = fmaf(x.x,w.x,fmaf(x.y,w.y,fmaf(x.z,w.z,fmaf(x.w,w.w,a2))));
            w = r3[q]; a3 = fmaf(x.x,w.x,fmaf(x.y,w.y,fmaf(x.z,w.z,fmaf(x.w,w.w,a3))));
            if (extra) { w = r4[q]; a4 = fmaf(x.x,w.x,fmaf(x.y,w.y,fmaf(x.z,w.z,fmaf(x.w,w.w,a4)))); }
        }
        sdbc[ll8][dbc_slot(j8)]      = a0;
        sdbc[ll8][dbc_slot(j8 + 8)]  = a1;
        sdbc[ll8][dbc_slot(j8 + 16)] = a2;
        sdbc[ll8][dbc_slot(j8 + 24)] = a3;
        if (extra) sdbc[ll8][dbc_slot(j8 + 32)] = a4;
    }
    __syncthreads();

    // A3: delta/delta*xi/g to registers, coalesced [t][d] float4 stores
    {
        const size_t tile = ((size_t)(c * 32 + b) * 8 + cq) * 4096;
        float dt0 = sdbc[ll8][0], dt1 = sdbc[ll8][1];
        float x3 = sseq4[ll8 + 3];
        float ybp = 0.f;
        float pdv[8], pxv[8], pgv[8];
#pragma unroll
        for (int k = 0; k < 8; ++k) {
            int di = j8 * 8 + k;
            float xi = sxi[ll8][di];
            float pre = fmaf(dt0, sdtw[di][0], fmaf(dt1, sdtw[di][1], sdtb[di]));
            float sp = (pre > 20.f) ? pre : log1pf(__expf(pre));
            float zv = fmaf(x3, su[64 + di], sv[64 + di]);
            float g = (zv / (1.f + __expf(-zv))) * swf[di];
            pdv[k] = sp;
            pxv[k] = sp * xi;
            pgv[k] = g;
            ybp = fmaf(g * sD[di], xi, ybp);
        }
        float* bp = ws + OFF_PD + tile + ll8 * 64 + j8 * 8;
        *reinterpret_cast<float4*>(bp)     = float4{pdv[0], pdv[1], pdv[2], pdv[3]};
        *reinterpret_cast<float4*>(bp + 4) = float4{pdv[4], pdv[5], pdv[6], pdv[7]};
        bp = ws + OFF_PX + tile + ll8 * 64 + j8 * 8;
        *reinterpret_cast<float4*>(bp)     = float4{pxv[0], pxv[1], pxv[2], pxv[3]};
        *reinterpret_cast<float4*>(bp + 4) = float4{pxv[4], pxv[5], pxv[6], pxv[7]};
        bp = ws + OFF_PG + tile + ll8 * 64 + j8 * 8;
        *reinterpret_cast<float4*>(bp)     = float4{pgv[0], pgv[1], pgv[2], pgv[3]};
        *reinterpret_cast<float4*>(bp + 4) = float4{pgv[4], pgv[5], pgv[6], pgv[7]};
        ybp += __shfl_xor(ybp, 1);
        ybp += __shfl_xor(ybp, 2);
        ybp += __shfl_xor(ybp, 4);
        if (j8 == 0) ws[OFF_YB + (size_t)(c * 32 + b) * 512 + gi] = ybp;
    }

    // B/C copy -> [s][t] layout (coalesced over t)
    {
        const size_t bb = ((size_t)(c * 32 + b) * 8 + cq) * 1024;
        for (int i = tid; i < 1024; i += 512) {
            int s = i >> 6, t = i & 63;
            ws[OFF_BCB + bb + i] = sdbc[t][2 + 2 * s];
            ws[OFF_BCC + bb + i] = sdbc[t][3 + 2 * s];
        }
    }
}

// DPP add over 16-lane rows
#define DPP_ADD(v, ctrl) ((v) + __int_as_float(__builtin_amdgcn_update_dpp(0, __float_as_int(v), (ctrl), 0xF, 0xF, true)))

// ksweep1: chunk-local h-only scan (h_in = 0). One block per (c,dq,b,chunk):
// 4096 blocks x 256 threads. Produces hE and aP = exp2(cA * sum(delta)).
__global__ __launch_bounds__(256, 4) void ksweep1(
    float* __restrict__ ws,
    const float* __restrict__ f_A_log, const float* __restrict__ b_A_log)
{
    const int tid = threadIdx.x;
    const int idx = blockIdx.x;          // ((c*4+dq)*32+b)*8+chunk
    const int chunk = idx & 7;
    const int b  = (idx >> 3) & 31;
    const int dq = (idx >> 8) & 3;
    const int c  = idx >> 10;
    const int dir = c & 1;
    const float* alog = dir ? b_A_log : f_A_log;

    const int dd = tid >> 4;
    const int s  = tid & 15;
    const int d  = dq * 16 + dd;
    const float cA = -expf(alog[d * 16 + s]) * 1.44269504088896340736f;

    __shared__ float sd[16][68], sx[16][68];

    const int st = tid >> 2;
    const int sc = (tid & 3) * 4;
    const size_t tb = (size_t)(c * 32 + b) * 8 + chunk;
    {
        const float* pd = ws + OFF_PD + tb * 4096;   // [t][64]
        const float* px = ws + OFF_PX + tb * 4096;
        float4 vd = *reinterpret_cast<const float4*>(pd + st * 64 + dq * 16 + sc);
        float4 vx = *reinterpret_cast<const float4*>(px + st * 64 + dq * 16 + sc);
        sd[sc + 0][st] = vd.x; sd[sc + 1][st] = vd.y; sd[sc + 2][st] = vd.z; sd[sc + 3][st] = vd.w;
        sx[sc + 0][st] = vx.x; sx[sc + 1][st] = vx.y; sx[sc + 2][st] = vx.z; sx[sc + 3][st] = vx.w;
    }
    __syncthreads();

    float h = 0.f, Sd = 0.f;
#pragma unroll 4
    for (int m = 0; m < 16; ++m) {
        float4 de = *reinterpret_cast<const float4*>(&sd[dd][4 * m]);
        float4 dx = *reinterpret_cast<const float4*>(&sx[dd][4 * m]);
        float a;
        a = exp2f(de.x * cA); h = fmaf(a, h, dx.x);
        a = exp2f(de.y * cA); h = fmaf(a, h, dx.y);
        a = exp2f(de.z * cA); h = fmaf(a, h, dx.z);
        a = exp2f(de.w * cA); h = fmaf(a, h, dx.w);
        Sd += de.x + de.y + de.z + de.w;
    }
    // NOTE: h here accumulates with dx (delta*xi) WITHOUT the B factor — WRONG?
    // No: the recurrence needs dx*B. B depends on s; include it:
    // (corrected below — this kernel re-reads B)
    // -- see ksweep1b structure: we fold B in during the loop instead.
    (void)h;
    // Recompute with B staged:
    __shared__ float sB[16][68];
    {
        const float* pB = ws + OFF_BCB + tb * 1024;  // [s][t]
        const int srow = tid >> 4;
        const int scol = (tid & 15) * 4;
        *reinterpret_cast<float4*>(&sB[srow][scol]) =
            *reinterpret_cast<const float4*>(pB + srow * 64 + scol);
    }
    __syncthreads();
    h = 0.f;
#pragma unroll 2
    for (int m = 0; m < 16; ++m) {
        float4 de = *reinterpret_cast<const float4*>(&sd[dd][4 * m]);
        float4 dx = *reinterpret_cast<const float4*>(&sx[dd][4 * m]);
        float4 Bq = *reinterpret_cast<const float4*>(&sB[s][4 * m]);
        float a;
        a = exp2f(de.x * cA); h = fmaf(a, h, dx.x * Bq.x);
        a = exp2f(de.y * cA); h = fmaf(a, h, dx.y * Bq.y);
        a = exp2f(de.z * cA); h = fmaf(a, h, dx.z * Bq.z);
        a = exp2f(de.w * cA); h = fmaf(a, h, dx.w * Bq.w);
    }
    ws[OFF_HE + (size_t)idx * 256 + tid] = h;
    ws[OFF_AP + (size_t)idx * 256 + tid] = exp2f(cA * Sd);
}

// kcomb: combine chunk summaries -> incoming states. 512 blocks x 256 thr.
__global__ __launch_bounds__(256, 4) void kcomb(float* __restrict__ ws)
{
    const int tid = threadIdx.x;
    const int base = blockIdx.x * 8;     // ((c*4+dq)*32+b)*8
    float hin = 0.f;
#pragma unroll
    for (int k = 0; k < 8; ++k) {
        ws[OFF_HIN + (size_t)(base + k) * 256 + tid] = hin;
        float aP = ws[OFF_AP + (size_t)(base + k) * 256 + tid];
        float hE = ws[OFF_HE + (size_t)(base + k) * 256 + tid];
        hin = fmaf(aP, hin, hE);
    }
}

// ksweep2: full scan of ONE chunk seeded with hin. 4096 blocks x 256 threads
// (4 waves/SIMD vs old kscan's 2 — the occupancy lever this round tests).
__global__ __launch_bounds__(256, 4) void ksweep2(
    float* __restrict__ ws,
    const float* __restrict__ f_A_log, const float* __restrict__ b_A_log)
{
    const int tid = threadIdx.x;
    const int idx = blockIdx.x;
    const int chunk = idx & 7;
    const int b  = (idx >> 3) & 31;
    const int dq = (idx >> 8) & 3;
    const int c  = idx >> 10;
    const int dir = c & 1;
    const float* alog = dir ? b_A_log : f_A_log;

    const int dd = tid >> 4;
    const int s  = tid & 15;
    const int d  = dq * 16 + dd;
    const float cA = -expf(alog[d * 16 + s]) * 1.44269504088896340736f;

    __shared__ float sd[16][68], sx[16][68], sg[16][68];
    __shared__ float sB[16][68], sC[16][68];
    __shared__ float syT[16][68];
    __shared__ float syb[64];

    const int srow = tid >> 4;
    const int scol = (tid & 15) * 4;
    const int st = tid >> 2;
    const int sc = (tid & 3) * 4;
    float* ypart = ws + OFF_YPART;
    const size_t tb = (size_t)(c * 32 + b) * 8 + chunk;

    {
        const float* pd = ws + OFF_PD + tb * 4096;
        const float* px = ws + OFF_PX + tb * 4096;
        const float* pg = ws + OFF_PG + tb * 4096;
        const float* pB = ws + OFF_BCB + tb * 1024;
        const float* pC = ws + OFF_BCC + tb * 1024;
        float4 vd = *reinterpret_cast<const float4*>(pd + st * 64 + dq * 16 + sc);
        float4 vx = *reinterpret_cast<const float4*>(px + st * 64 + dq * 16 + sc);
        float4 vg = *reinterpret_cast<const float4*>(pg + st * 64 + dq * 16 + sc);
        sd[sc + 0][st] = vd.x; sd[sc + 1][st] = vd.y; sd[sc + 2][st] = vd.z; sd[sc + 3][st] = vd.w;
        sx[sc + 0][st] = vx.x; sx[sc + 1][st] = vx.y; sx[sc + 2][st] = vx.z; sx[sc + 3][st] = vx.w;
        sg[sc + 0][st] = vg.x; sg[sc + 1][st] = vg.y; sg[sc + 2][st] = vg.z; sg[sc + 3][st] = vg.w;
        *reinterpret_cast<float4*>(&sB[srow][scol]) =
            *reinterpret_cast<const float4*>(pB + srow * 64 + scol);
        *reinterpret_cast<float4*>(&sC[srow][scol]) =
            *reinterpret_cast<const float4*>(pC + srow * 64 + scol);
        if (dq == 0 && tid < 64) syb[tid] = ws[OFF_YB + (size_t)(c * 32 + b) * 512 + chunk * 64 + tid];
    }
    float h = ws[OFF_HIN + (size_t)idx * 256 + tid];
    __syncthreads();

    {
#pragma unroll 2
        for (int m = 0; m < 16; ++m) {
            float4 de = *reinterpret_cast<const float4*>(&sd[dd][4 * m]);
            float4 dx = *reinterpret_cast<const float4*>(&sx[dd][4 * m]);
            float4 gq = *reinterpret_cast<const float4*>(&sg[dd][4 * m]);
            float4 Bq = *reinterpret_cast<const float4*>(&sB[s][4 * m]);
            float4 Cq = *reinterpret_cast<const float4*>(&sC[s][4 * m]);
            float4 val;
            float a, pc;
            a = exp2f(de.x * cA); h = fmaf(a, h, dx.x * Bq.x); pc = h * Cq.x;
            pc = DPP_ADD(pc, 0x101); pc = DPP_ADD(pc, 0x102);
            pc = DPP_ADD(pc, 0x104); pc = DPP_ADD(pc, 0x108);
            val.x = pc * gq.x;
            a = exp2f(de.y * cA); h = fmaf(a, h, dx.y * Bq.y); pc = h * Cq.y;
            pc = DPP_ADD(pc, 0x101); pc = DPP_ADD(pc, 0x102);
            pc = DPP_ADD(pc, 0x104); pc = DPP_ADD(pc, 0x108);
            val.y = pc * gq.y;
            a = exp2f(de.z * cA); h = fmaf(a, h, dx.z * Bq.z); pc = h * Cq.z;
            pc = DPP_ADD(pc, 0x101); pc = DPP_ADD(pc, 0x102);
            pc = DPP_ADD(pc, 0x104); pc = DPP_ADD(pc, 0x108);
            val.z = pc * gq.z;
            a = exp2f(de.w * cA); h = fmaf(a, h, dx.w * Bq.w); pc = h * Cq.w;
            pc = DPP_ADD(pc, 0x101); pc = DPP_ADD(pc, 0x102);
            pc = DPP_ADD(pc, 0x104); pc = DPP_ADD(pc, 0x108);
            val.w = pc * gq.w;
            if (s == 0) *reinterpret_cast<float4*>(&syT[dd][4 * m]) = val;
        }
    }
    __syncthreads();

    // fold over 16 dd -> scalar partial into slot (c*4 + dq)
    {
        const int tt4 = tid >> 2;
        const int j4  = tid & 3;
        float acc = syT[j4 * 4][tt4] + syT[j4 * 4 + 1][tt4]
                  + syT[j4 * 4 + 2][tt4] + syT[j4 * 4 + 3][tt4];
        acc += __shfl_xor(acc, 1);
        acc += __shfl_xor(acc, 2);
        if (j4 == 0) {
            int i = chunk * 64 + tt4;
            int l = dir ? (511 - i) : i;
            float res = acc + (dq == 0 ? syb[tt4] : 0.f);
            ypart[((c * 4 + dq) * 32 + b) * 512 + l] = res;
        }
    }
}

__global__ __launch_bounds__(256) void kfinal(const float* __restrict__ xavg,
                                              const float* __restrict__ xmax,
                                              const float* __restrict__ ypart,
                                              const float* __restrict__ gate_w,
                                              const float* __restrict__ gate_b,
                                              const float* __restrict__ out_b,
                                              float* __restrict__ out) {
    const int idx = blockIdx.x * 256 + threadIdx.x;
    float xa = xavg[idx], xm = xmax[idx];
    float alpha = 1.f / (1.f + __expf(-(fmaf(xa, gate_w[0], fmaf(xm, gate_w[1], gate_b[0])))));
    float sa = 0.f, sm = 0.f;
#pragma unroll
    for (int k = 0; k < 8; ++k)  sa += ypart[k * 16384 + idx];
#pragma unroll
    for (int k = 8; k < 16; ++k) sm += ypart[k * 16384 + idx];
    float y = alpha * sa + (1.f - alpha) * sm + out_b[0];
    out[idx] = 1.f / (1.f + __expf(-y));
}

extern "C" void kernel_launch(void* const* d_in, const int* in_sizes, int n_in,
                              void* d_out, int out_size, void* d_ws, size_t ws_size,
                              hipStream_t stream) {
    const float* inp = (const float*)d_in[0];
    const float* paw = (const float*)d_in[1];
    const float* pab = (const float*)d_in[2];
    const float* pmw = (const float*)d_in[3];
    const float* pmb = (const float*)d_in[4];
    const float* gw  = (const float*)d_in[5];
    const float* gb  = (const float*)d_in[6];
    const float* ow  = (const float*)d_in[7];
    const float* ob  = (const float*)d_in[8];

    float* ws = (float*)d_ws;
    float* xavg = ws;
    float* xmax = ws + 16384;
    float* ypart = ws + OFF_YPART;
    float* out = (float*)d_out;

    kconst<<<4, 128, 0, stream>>>(
        ws, paw, pab, pmw, pmb, ow,
        (const float*)d_in[9], (const float*)d_in[17],
        (const float*)d_in[18], (const float*)d_in[26]);
    kreduce<<<16384, 256, 0, stream>>>(inp, xavg, xmax);
    kprep<<<1024, 512, 0, stream>>>(
        xavg, xmax, ws,
        (const float*)d_in[10], (const float*)d_in[11], (const float*)d_in[12],
        (const float*)d_in[13], (const float*)d_in[14], (const float*)d_in[16],
        (const float*)d_in[19], (const float*)d_in[20], (const float*)d_in[21],
        (const float*)d_in[22], (const float*)d_in[23], (const float*)d_in[25]);
    ksweep1<<<4096, 256, 0, stream>>>(
        ws, (const float*)d_in[15], (const float*)d_in[24]);
    kcomb<<<512, 256, 0, stream>>>(ws);
    ksweep2<<<4096, 256, 0, stream>>>(
        ws, (const float*)d_in[15], (const float*)d_in[24]);
    kfinal<<<64, 256, 0, stream>>>(xavg, xmax, ypart, gw, gb, ob, out);
}

// Round 18
// 126.067 us; speedup vs baseline: 1.1526x; 1.1526x over previous
//
#include <hip/hip_runtime.h>
#include <math.h>

// ws float-offset layout (ws >= 1 GiB, we use ~56 MB):
// xavg  [0, 16384)
// xmax  [16384, 32768)
// ypart [32768, 294912)                16 slots x 16384: slot = c*4 + dquarter
// PD    [294912, +4194304)             delta^T   [c][b][chunk][d][t]  (64x64 tiles)
// PX    PD+4194304                     delta*xi^T
// PG    PX+4194304                     g^T  (silu(z)*wfold)
// BCB   PG+4194304 (+524288)           B [c][b][chunk][s][t]
// BCC   BCB+524288                     C [c][b][chunk][s][t]
// YB    BCC+524288 (+65536)            ybase [c][b][t]
#define OFF_YPART 32768
#define OFF_PD    294912
#define OFF_PX    (OFF_PD + 4194304)
#define OFF_PG    (OFF_PX + 4194304)
#define OFF_BCB   (OFF_PG + 4194304)
#define OFF_BCC   (OFF_BCB + 524288)
#define OFF_YB    (OFF_BCC + 524288)

__global__ __launch_bounds__(256) void kreduce(const float* __restrict__ in,
                                               float* __restrict__ xavg,
                                               float* __restrict__ xmax) {
    const int bl = blockIdx.x;            // 0..16383  (= b*512 + l)
    const float* p = in + (size_t)bl * 4096;
    const int t = threadIdx.x;
    float s = 0.f, m = -INFINITY;
#pragma unroll
    for (int it = 0; it < 4; ++it) {
        float4 v = *reinterpret_cast<const float4*>(p + (size_t)(it * 256 + t) * 4);
        s += v.x + v.y + v.z + v.w;
        m = fmaxf(m, fmaxf(fmaxf(v.x, v.y), fmaxf(v.z, v.w)));
    }
#pragma unroll
    for (int o = 1; o < 64; o <<= 1) {
        s += __shfl_xor(s, o);
        m = fmaxf(m, __shfl_xor(m, o));
    }
    __shared__ float ls[4], lm[4];
    const int w = t >> 6;
    if ((t & 63) == 0) { ls[w] = s; lm[w] = m; }
    __syncthreads();
    if (t == 0) {
        s = ls[0] + ls[1] + ls[2] + ls[3];
        m = fmaxf(fmaxf(lm[0], lm[1]), fmaxf(lm[2], lm[3]));
        xavg[bl] = s * (1.f / 4096.f);
        xmax[bl] = m;
    }
}

// slot of dbc j-index (j: 0,1=dt; 2..17=B; 18..33=C) in interleaved record
__device__ __forceinline__ int dbc_slot(int j) {
    return j < 2 ? j : (j < 18 ? 2 * j - 2 : 2 * j - 33);
}

// kprep: A-phases + full A3 precompute, pre-transposed outputs.
// One block per (c, b, chunk): 4*32*8 = 1024 blocks x 512 threads (4 blocks/CU).
// NOTE: plain __launch_bounds__(512) — r12's (512,4) min-waves arg is a VGPR
// CAP, not a floor, and coincided with a +8.5us regression. Session optimum
// (r11, 125.9us) used the plain form; reverted to it.
__global__ __launch_bounds__(512) void kprep(
    const float* __restrict__ xavg, const float* __restrict__ xmax,
    float* __restrict__ ws,
    const float* __restrict__ paw, const float* __restrict__ pab,
    const float* __restrict__ pmw, const float* __restrict__ pmb,
    const float* __restrict__ outw_outer,
    const float* __restrict__ f_in_w, const float* __restrict__ f_conv_w,
    const float* __restrict__ f_conv_b, const float* __restrict__ f_xproj_w,
    const float* __restrict__ f_dt_w, const float* __restrict__ f_dt_b,
    const float* __restrict__ f_D, const float* __restrict__ f_out_w,
    const float* __restrict__ b_in_w, const float* __restrict__ b_conv_w,
    const float* __restrict__ b_conv_b, const float* __restrict__ b_xproj_w,
    const float* __restrict__ b_dt_w, const float* __restrict__ b_dt_b,
    const float* __restrict__ b_D, const float* __restrict__ b_out_w)
{
    const int tid = threadIdx.x;
    const int c  = blockIdx.x >> 8;
    const int b  = (blockIdx.x >> 3) & 31;
    const int cq = blockIdx.x & 7;
    const int strm = c >> 1, dir = c & 1;

    const float* in_w = dir ? b_in_w   : f_in_w;
    const float* cwp  = dir ? b_conv_w : f_conv_w;
    const float* cbp  = dir ? b_conv_b : f_conv_b;
    const float* xpw  = dir ? b_xproj_w: f_xproj_w;
    const float* dtwp = dir ? b_dt_w   : f_dt_w;
    const float* dtbp = dir ? b_dt_b   : f_dt_b;
    const float* Dpar = dir ? b_D      : f_D;
    const float* owp  = dir ? b_out_w  : f_out_w;
    const float* projw = strm ? pmw : paw;
    const float* projb = strm ? pmb : pab;
    const float* xin   = strm ? xmax : xavg;

    __shared__ float sseq4[68];       // x at t = cq*64-3+i (scan order), 0 for OOB
    __shared__ float su[128], sv[128];
    __shared__ float scw[64][4], scb[64], sdtw[64][2], sdtb[64], sD[64], swf[64];
    __shared__ float sxp[34][68];
    __shared__ float sxi[64][68];
    __shared__ float sdbc[64][37];    // pad 37: conflict-free-ish strided column reads

    if (tid < 67) {
        int g = cq * 64 - 3 + tid;
        float val = 0.f;
        if (g >= 0) val = xin[b * 512 + (dir ? (511 - g) : g)];
        sseq4[tid] = val;
    }
    if (tid < 128) {
        float u = 0.f, v = 0.f;
        const float* row = in_w + tid * 32;
#pragma unroll
        for (int m = 0; m < 32; ++m) {
            u = fmaf(row[m], projw[m], u);
            v = fmaf(row[m], projb[m], v);
        }
        su[tid] = u; sv[tid] = v;
    }
    if (tid < 64) {
#pragma unroll
        for (int k = 0; k < 4; ++k) scw[tid][k] = cwp[tid * 4 + k];
        scb[tid] = cbp[tid];
        sdtw[tid][0] = dtwp[tid * 2];
        sdtw[tid][1] = dtwp[tid * 2 + 1];
        sdtb[tid] = dtbp[tid];
        sD[tid] = Dpar[tid];
        float wf = 0.f;
#pragma unroll
        for (int m = 0; m < 32; ++m) wf = fmaf(outw_outer[m], owp[m * 64 + tid], wf);
        swf[tid] = wf;
    }
    for (int i = tid; i < 34 * 64; i += 512) sxp[i >> 6][i & 63] = xpw[i];
    __syncthreads();

    const int ll8 = tid >> 3;  // 0..63 (t within chunk)
    const int j8  = tid & 7;
    const int gi  = cq * 64 + ll8;   // global t (scan order)

    // A1: xi for all 64 d
    {
        float t0 = sseq4[ll8], t1 = sseq4[ll8 + 1], t2 = sseq4[ll8 + 2], t3 = sseq4[ll8 + 3];
        float vv0 = (gi >= 3) ? 1.f : 0.f;
        float vv1 = (gi >= 2) ? 1.f : 0.f;
        float vv2 = (gi >= 1) ? 1.f : 0.f;
#pragma unroll
        for (int k = 0; k < 8; ++k) {
            int di = j8 * 8 + k;
            float u = su[di], v = sv[di];
            float xc = scw[di][0] * fmaf(t0, u, vv0 * v)
                     + scw[di][1] * fmaf(t1, u, vv1 * v)
                     + scw[di][2] * fmaf(t2, u, vv2 * v)
                     + scw[di][3] * fmaf(t3, u, v);
            xc += scb[di];
            float sig = 1.f / (1.f + __expf(-xc));
            sxi[ll8][di] = xc * sig;
        }
    }
    __syncthreads();

    // A2: dbc = xi @ xproj_w.T -> LDS records (interleaved layout).
    // unroll 2 only: full unroll spills past the VGPR budget (rounds 2-8 lesson).
    {
        float a0 = 0.f, a1 = 0.f, a2 = 0.f, a3 = 0.f, a4 = 0.f;
        const float4* xr4 = reinterpret_cast<const float4*>(&sxi[ll8][0]);
        const float4* r0 = reinterpret_cast<const float4*>(&sxp[j8 + 0][0]);
        const float4* r1 = reinterpret_cast<const float4*>(&sxp[j8 + 8][0]);
        const float4* r2 = reinterpret_cast<const float4*>(&sxp[j8 + 16][0]);
        const float4* r3 = reinterpret_cast<const float4*>(&sxp[j8 + 24][0]);
        const float4* r4 = (j8 < 2) ? reinterpret_cast<const float4*>(&sxp[j8 + 32][0]) : r0;
        bool extra = (j8 < 2);
#pragma unroll 2
        for (int q = 0; q < 16; ++q) {
            float4 x = xr4[q];
            float4 w;
            w = r0[q]; a0 = fmaf(x.x,w.x,fmaf(x.y,w.y,fmaf(x.z,w.z,fmaf(x.w,w.w,a0))));
            w = r1[q]; a1 = fmaf(x.x,w.x,fmaf(x.y,w.y,fmaf(x.z,w.z,fmaf(x.w,w.w,a1))));
            w = r2[q]; a2 = fmaf(x.x,w.x,fmaf(x.y,w.y,fmaf(x.z,w.z,fmaf(x.w,w.w,a2))));
            w = r3[q]; a3 = fmaf(x.x,w.x,fmaf(x.y,w.y,fmaf(x.z,w.z,fmaf(x.w,w.w,a3))));
            if (extra) { w = r4[q]; a4 = fmaf(x.x,w.x,fmaf(x.y,w.y,fmaf(x.z,w.z,fmaf(x.w,w.w,a4)))); }
        }
        sdbc[ll8][dbc_slot(j8)]      = a0;
        sdbc[ll8][dbc_slot(j8 + 8)]  = a1;
        sdbc[ll8][dbc_slot(j8 + 16)] = a2;
        sdbc[ll8][dbc_slot(j8 + 24)] = a3;
        if (extra) sdbc[ll8][dbc_slot(j8 + 32)] = a4;
    }
    __syncthreads();

    // A3: delta (softplus via __logf), delta*xi, g = silu(z)*wfold, ybase -> global transposed
    {
        const size_t tile = ((size_t)(c * 32 + b) * 8 + cq) * 4096;
        float dt0 = sdbc[ll8][0], dt1 = sdbc[ll8][1];
        float x3 = sseq4[ll8 + 3];   // = x[gi]
        float ybp = 0.f;
#pragma unroll 2
        for (int k = 0; k < 8; ++k) {
            int di = j8 * 8 + k;
            float xi = sxi[ll8][di];
            float pre = fmaf(dt0, sdtw[di][0], fmaf(dt1, sdtw[di][1], sdtb[di]));
            float sp = (pre > 20.f) ? pre : __logf(1.f + __expf(pre));
            float zv = fmaf(x3, su[64 + di], sv[64 + di]);
            float g = (zv / (1.f + __expf(-zv))) * swf[di];
            ws[OFF_PD + tile + di * 64 + ll8] = sp;
            ws[OFF_PX + tile + di * 64 + ll8] = sp * xi;
            ws[OFF_PG + tile + di * 64 + ll8] = g;
            ybp = fmaf(g * sD[di], xi, ybp);
        }
        ybp += __shfl_xor(ybp, 1);
        ybp += __shfl_xor(ybp, 2);
        ybp += __shfl_xor(ybp, 4);
        if (j8 == 0) ws[OFF_YB + (size_t)(c * 32 + b) * 512 + gi] = ybp;
    }

    // B/C copy -> [s][t] layout (coalesced over t)
    {
        const size_t bb = ((size_t)(c * 32 + b) * 8 + cq) * 1024;
        for (int i = tid; i < 1024; i += 512) {
            int s = i >> 6, t = i & 63;
            ws[OFF_BCB + bb + i] = sdbc[t][2 + 2 * s];
            ws[OFF_BCC + bb + i] = sdbc[t][3 + 2 * s];
        }
    }
}

// DPP add over 16-lane rows: after shl 1,2,4,8, lane (s==0) holds the row sum.
#define DPP_ADD(v, ctrl) ((v) + __int_as_float(__builtin_amdgcn_update_dpp(0, __float_as_int(v), (ctrl), 0xF, 0xF, true)))

// kscan: pure scan. One block per (c, dquarter, b): 4*4*32 = 512 blocks x 256 threads.
__global__ __launch_bounds__(256) void kscan(
    float* __restrict__ ws,
    const float* __restrict__ f_A_log, const float* __restrict__ b_A_log)
{
    const int tid = threadIdx.x;
    const int c  = blockIdx.x >> 7;
    const int dq = (blockIdx.x >> 5) & 3;
    const int b  = blockIdx.x & 31;
    const int dir = c & 1;
    const float* alog = dir ? b_A_log : f_A_log;

    const int dd = tid >> 4;          // 0..15 (local d in quarter)
    const int s  = tid & 15;
    const int d  = dq * 16 + dd;      // global d 0..63
    const float cA = -expf(alog[d * 16 + s]) * 1.44269504088896340736f;
    float h = 0.f;

    __shared__ float sd[16][68], sx[16][68], sg[16][68];
    __shared__ float sB[16][68], sC[16][68];
    __shared__ float syT[16][68];
    __shared__ float syb[64];

    // staging map: 256 thr = 16 rows x 16 col-quads
    const int srow = tid >> 4;
    const int scol = (tid & 15) * 4;
    float* ypart = ws + OFF_YPART;

    for (int chunk = 0; chunk < 8; ++chunk) {
        const size_t tb = (size_t)(c * 32 + b) * 8 + chunk;
        const float* pd = ws + OFF_PD + tb * 4096 + dq * 1024;
        const float* px = ws + OFF_PX + tb * 4096 + dq * 1024;
        const float* pg = ws + OFF_PG + tb * 4096 + dq * 1024;
        const float* pB = ws + OFF_BCB + tb * 1024;
        const float* pC = ws + OFF_BCC + tb * 1024;

        // stage (straight coalesced copies; layouts already match)
        *reinterpret_cast<float4*>(&sd[srow][scol]) =
            *reinterpret_cast<const float4*>(pd + srow * 64 + scol);
        *reinterpret_cast<float4*>(&sx[srow][scol]) =
            *reinterpret_cast<const float4*>(px + srow * 64 + scol);
        *reinterpret_cast<float4*>(&sg[srow][scol]) =
            *reinterpret_cast<const float4*>(pg + srow * 64 + scol);
        *reinterpret_cast<float4*>(&sB[srow][scol]) =
            *reinterpret_cast<const float4*>(pB + srow * 64 + scol);
        *reinterpret_cast<float4*>(&sC[srow][scol]) =
            *reinterpret_cast<const float4*>(pC + srow * 64 + scol);
        if (dq == 0 && tid < 64) syb[tid] = ws[OFF_YB + (size_t)(c * 32 + b) * 512 + chunk * 64 + tid];
        __syncthreads();

        // scan 16 m-iters x 4 steps; h carried across chunks
        {
#pragma unroll 2
            for (int m = 0; m < 16; ++m) {
                float4 de = *reinterpret_cast<const float4*>(&sd[dd][4 * m]);
                float4 dx = *reinterpret_cast<const float4*>(&sx[dd][4 * m]);
                float4 gq = *reinterpret_cast<const float4*>(&sg[dd][4 * m]);
                float4 Bq = *reinterpret_cast<const float4*>(&sB[s][4 * m]);
                float4 Cq = *reinterpret_cast<const float4*>(&sC[s][4 * m]);
                float4 val;
                float a, pc;
                a = exp2f(de.x * cA); h = fmaf(a, h, dx.x * Bq.x); pc = h * Cq.x;
                pc = DPP_ADD(pc, 0x101); pc = DPP_ADD(pc, 0x102);
                pc = DPP_ADD(pc, 0x104); pc = DPP_ADD(pc, 0x108);
                val.x = pc * gq.x;
                a = exp2f(de.y * cA); h = fmaf(a, h, dx.y * Bq.y); pc = h * Cq.y;
                pc = DPP_ADD(pc, 0x101); pc = DPP_ADD(pc, 0x102);
                pc = DPP_ADD(pc, 0x104); pc = DPP_ADD(pc, 0x108);
                val.y = pc * gq.y;
                a = exp2f(de.z * cA); h = fmaf(a, h, dx.z * Bq.z); pc = h * Cq.z;
                pc = DPP_ADD(pc, 0x101); pc = DPP_ADD(pc, 0x102);
                pc = DPP_ADD(pc, 0x104); pc = DPP_ADD(pc, 0x108);
                val.z = pc * gq.z;
                a = exp2f(de.w * cA); h = fmaf(a, h, dx.w * Bq.w); pc = h * Cq.w;
                pc = DPP_ADD(pc, 0x101); pc = DPP_ADD(pc, 0x102);
                pc = DPP_ADD(pc, 0x104); pc = DPP_ADD(pc, 0x108);
                val.w = pc * gq.w;
                if (s == 0) *reinterpret_cast<float4*>(&syT[dd][4 * m]) = val;
            }
        }
        __syncthreads();

        // fold over 16 dd -> scalar partial into slot (c*4 + dq)
        {
            const int tt4 = tid >> 2;   // 0..63
            const int j4  = tid & 3;
            float acc = syT[j4 * 4][tt4] + syT[j4 * 4 + 1][tt4]
                      + syT[j4 * 4 + 2][tt4] + syT[j4 * 4 + 3][tt4];
            acc += __shfl_xor(acc, 1);
            acc += __shfl_xor(acc, 2);
            if (j4 == 0) {
                int i = chunk * 64 + tt4;
                int l = dir ? (511 - i) : i;
                float res = acc + (dq == 0 ? syb[tt4] : 0.f);
                ypart[((c * 4 + dq) * 32 + b) * 512 + l] = res;
            }
        }
        __syncthreads();
    }
}

__global__ __launch_bounds__(256) void kfinal(const float* __restrict__ xavg,
                                              const float* __restrict__ xmax,
                                              const float* __restrict__ ypart,
                                              const float* __restrict__ gate_w,
                                              const float* __restrict__ gate_b,
                                              const float* __restrict__ out_b,
                                              float* __restrict__ out) {
    const int idx = blockIdx.x * 256 + threadIdx.x;   // 0..16383
    float xa = xavg[idx], xm = xmax[idx];
    float alpha = 1.f / (1.f + __expf(-(fmaf(xa, gate_w[0], fmaf(xm, gate_w[1], gate_b[0])))));
    float sa = 0.f, sm = 0.f;
#pragma unroll
    for (int k = 0; k < 8; ++k)  sa += ypart[k * 16384 + idx];
#pragma unroll
    for (int k = 8; k < 16; ++k) sm += ypart[k * 16384 + idx];
    float y = alpha * sa + (1.f - alpha) * sm + out_b[0];
    out[idx] = 1.f / (1.f + __expf(-y));
}

extern "C" void kernel_launch(void* const* d_in, const int* in_sizes, int n_in,
                              void* d_out, int out_size, void* d_ws, size_t ws_size,
                              hipStream_t stream) {
    const float* inp = (const float*)d_in[0];
    const float* paw = (const float*)d_in[1];
    const float* pab = (const float*)d_in[2];
    const float* pmw = (const float*)d_in[3];
    const float* pmb = (const float*)d_in[4];
    const float* gw  = (const float*)d_in[5];
    const float* gb  = (const float*)d_in[6];
    const float* ow  = (const float*)d_in[7];
    const float* ob  = (const float*)d_in[8];

    float* ws = (float*)d_ws;
    float* xavg = ws;
    float* xmax = ws + 16384;
    float* ypart = ws + OFF_YPART;
    float* out = (float*)d_out;

    kreduce<<<16384, 256, 0, stream>>>(inp, xavg, xmax);
    kprep<<<1024, 512, 0, stream>>>(
        xavg, xmax, ws, paw, pab, pmw, pmb, ow,
        (const float*)d_in[9],  (const float*)d_in[10], (const float*)d_in[11], (const float*)d_in[12],
        (const float*)d_in[13], (const float*)d_in[14], (const float*)d_in[16], (const float*)d_in[17],
        (const float*)d_in[18], (const float*)d_in[19], (const float*)d_in[20], (const float*)d_in[21],
        (const float*)d_in[22], (const float*)d_in[23], (const float*)d_in[25], (const float*)d_in[26]);
    kscan<<<512, 256, 0, stream>>>(
        ws, (const float*)d_in[15], (const float*)d_in[24]);
    kfinal<<<64, 256, 0, stream>>>(xavg, xmax, ypart, gw, gb, ob, out);
}